// Round 6
// baseline (301.945 us; speedup 1.0000x reference)
//
#include <hip/hip_runtime.h>

typedef unsigned short u16;
typedef unsigned int u32;
typedef __attribute__((ext_vector_type(8))) __bf16 bf16x8;
typedef __attribute__((ext_vector_type(8))) _Float16 f16x8;
typedef __attribute__((ext_vector_type(4))) float f32x4;

// ---------- helpers ----------
__device__ __forceinline__ float b2f(u16 b) {
    union { u32 u; float f; } v; v.u = ((u32)b) << 16; return v.f;
}
// native RNE f32->bf16 (v_cvt_pk_bf16_f32)
__device__ __forceinline__ u16 f2bf(float f) {
    return __builtin_bit_cast(u16, (__bf16)f);
}
__device__ __forceinline__ u16 f2h(float f) {
    _Float16 h = (_Float16)f;
    return __builtin_bit_cast(u16, h);
}
// packed pair -> u32 (compiler emits v_cvt_pk_bf16_f32)
__device__ __forceinline__ u32 pkbf2(float a, float b) {
    u16 x = __builtin_bit_cast(u16, (__bf16)a);
    u16 y = __builtin_bit_cast(u16, (__bf16)b);
    return (u32)x | ((u32)y << 16);
}
__device__ __forceinline__ bf16x8 ldg8b(const u16* p) {
    uint4 v = *(const uint4*)p;
    return __builtin_bit_cast(bf16x8, v);
}
__device__ __forceinline__ f16x8 ldg8h(const u16* p) {
    uint4 v = *(const uint4*)p;
    return __builtin_bit_cast(f16x8, v);
}
__device__ __forceinline__ f32x4 mfma_bf(bf16x8 a, bf16x8 b, f32x4 c) {
    return __builtin_amdgcn_mfma_f32_16x16x32_bf16(a, b, c, 0, 0, 0);
}
__device__ __forceinline__ f32x4 mfma_h(f16x8 a, f16x8 b, f32x4 c) {
    return __builtin_amdgcn_mfma_f32_16x16x32_f16(a, b, c, 0, 0, 0);
}
// async global->LDS: lds dest = wave-uniform base + lane*16
__device__ __forceinline__ void gld16(const u16* g, u16* l) {
    __builtin_amdgcn_global_load_lds(
        (const __attribute__((address_space(1))) u32*)g,
        (__attribute__((address_space(3))) u32*)l, 16, 0, 0);
}

#define LOG2E 1.44269504088896340736f

// Q global layout: per batch, row p (4096): 64 fp16, elem slot = d ^ ((p&7)*8)
// Gt global layout: per (n, step s of 64 p): 16384 elems: ch*64 + ((pp&~7)^((ch&7)*8)) + (pp&7)

// ---------- K0: hi/lo bf16 split of W, transposed: Wt[d][c] ----------
__global__ void k0_wt(const float* __restrict__ Wq,
                      u16* __restrict__ Wthi, u16* __restrict__ Wtlo) {
    int idx = blockIdx.x * 256 + threadIdx.x;   // 64 blocks -> 16384
    int c = idx >> 6, d = idx & 63;
    float w = Wq[idx];
    u16 hi = f2bf(w);
    float rem = w - b2f(hi);
    Wthi[d * 256 + c] = hi;
    Wtlo[d * 256 + c] = f2bf(rem);
}

// ---------- K1: Q = F*W (hi/lo split MFMA), fp16 out, XOR-swizzled rows ----------
__global__ __launch_bounds__(256) void k1_query(
    const float* __restrict__ F, const u16* __restrict__ Wthi,
    const u16* __restrict__ Wtlo, u16* __restrict__ Qh) {
    const int t = threadIdx.x;
    const int w = t >> 6, L = t & 63, lane16 = L & 15, quad = L >> 4;
    const int R0 = blockIdx.x * 64;
    const int row = R0 + w * 16 + lane16;
    const f32x4 z4 = {0.f, 0.f, 0.f, 0.f};
    f32x4 acc[4] = {z4, z4, z4, z4};
    union U8 { bf16x8 v; u16 s[8]; };
#pragma unroll
    for (int ks = 0; ks < 8; ++ks) {
        const float* fp = F + (size_t)row * 256 + ks * 32 + quad * 8;
        float4 x0 = *(const float4*)fp;
        float4 x1 = *(const float4*)(fp + 4);
        float xs[8] = {x0.x, x0.y, x0.z, x0.w, x1.x, x1.y, x1.z, x1.w};
        U8 ahi, alo;
#pragma unroll
        for (int j = 0; j < 8; ++j) {
            u16 h = f2bf(xs[j]);
            ahi.s[j] = h;
            alo.s[j] = f2bf(xs[j] - b2f(h));
        }
#pragma unroll
        for (int nt = 0; nt < 4; ++nt) {
            const int off = (nt * 16 + lane16) * 256 + ks * 32 + quad * 8;
            bf16x8 bh = ldg8b(Wthi + off);
            bf16x8 bl = ldg8b(Wtlo + off);
            acc[nt] = mfma_bf(ahi.v, bh, acc[nt]);
            acc[nt] = mfma_bf(alo.v, bh, acc[nt]);
            acc[nt] = mfma_bf(ahi.v, bl, acc[nt]);
        }
    }
    const int orow = R0 + w * 16 + quad * 4;
#pragma unroll
    for (int nt = 0; nt < 4; ++nt) {
        const int d = nt * 16 + lane16;
#pragma unroll
        for (int r = 0; r < 4; ++r) {
            const int p = orow + r;
            Qh[(size_t)p * 64 + (d ^ ((p & 7) << 3))] = f2h(acc[nt][r]);
        }
    }
}

// ---------- K2: lgl[p] = -log2( sum_q exp(Q_p . Q_q) ) ----------
// v7: p-tile 64 (was 32), 512 threads, grid 512 -> halves the redundant
// all-Q L2 reads (64 blocks/batch instead of 128). Wave w covers q-range
// [w*512, (w+1)*512); 4 p-subtiles of 16 in registers.
__global__ __launch_bounds__(512) void k2_suminv(
    const u16* __restrict__ Q, float* __restrict__ lgl) {
    const int t = threadIdx.x;
    const int w = t >> 6, L = t & 63, lane16 = L & 15, quad = L >> 4, l7 = lane16 & 7;
    const int bx = blockIdx.x;
    const int n = bx & 7, pb = bx >> 3;   // batch-per-XCD swizzle
    const int P0 = pb * 64;
    const u16* Qn = Q + (size_t)n * 4096 * 64;

    f16x8 ap[4][2];
#pragma unroll
    for (int st = 0; st < 4; ++st) {
        const int row = P0 + st * 16 + lane16;
        ap[st][0] = ldg8h(Qn + row * 64 + ((quad * 8) ^ (l7 * 8)));
        ap[st][1] = ldg8h(Qn + row * 64 + ((32 + quad * 8) ^ (l7 * 8)));
    }
    float sums[4][4];
#pragma unroll
    for (int st = 0; st < 4; ++st)
#pragma unroll
        for (int r = 0; r < 4; ++r) sums[st][r] = 0.f;

    const f32x4 z4 = {0.f, 0.f, 0.f, 0.f};
    for (int s = 0; s < 16; ++s) {
#pragma unroll
        for (int nt = 0; nt < 2; ++nt) {
            const int qr = w * 512 + s * 32 + nt * 16 + lane16;
            f16x8 b0 = ldg8h(Qn + qr * 64 + ((quad * 8) ^ (l7 * 8)));
            f16x8 b1 = ldg8h(Qn + qr * 64 + ((32 + quad * 8) ^ (l7 * 8)));
#pragma unroll
            for (int st = 0; st < 4; ++st) {
                f32x4 z = z4;
                z = mfma_h(ap[st][0], b0, z);
                z = mfma_h(ap[st][1], b1, z);
                sums[st][0] += __expf(z[0]);
                sums[st][1] += __expf(z[1]);
                sums[st][2] += __expf(z[2]);
                sums[st][3] += __expf(z[3]);
            }
        }
    }
    __shared__ float red[8][64];
#pragma unroll
    for (int st = 0; st < 4; ++st)
#pragma unroll
        for (int r = 0; r < 4; ++r) {
            float v = sums[st][r];
            v += __shfl_xor(v, 1);
            v += __shfl_xor(v, 2);
            v += __shfl_xor(v, 4);
            v += __shfl_xor(v, 8);
            if (lane16 == 0) red[w][st * 16 + quad * 4 + r] = v;
        }
    __syncthreads();
    if (t < 64) {
        float tot = 0.f;
#pragma unroll
        for (int ww = 0; ww < 8; ++ww) tot += red[ww][t];
        lgl[n * 4096 + P0 + t] = -__log2f(tot);   // exp(z)/tot = exp2(z*log2e + lgl)
    }
}

// ---------- K3: Gt_sw[n][s][ch][p-swizzled] = bf16(F[n][p][ch]) ----------
__global__ __launch_bounds__(256) void k3_gt(
    const float* __restrict__ F, u16* __restrict__ Gt) {
    const int t = threadIdx.x;
    const int bx = blockIdx.x;                  // 512 = 8 n * 64 s
    const int n = bx >> 6, s = bx & 63;
    const int p0 = s * 64;
    __shared__ float tile[64][65];
    const float* Fn = F + (size_t)n * 4096 * 256;
    u16* Gn = Gt + (size_t)(n * 64 + s) * 16384;
#pragma unroll 1
    for (int ct = 0; ct < 4; ++ct) {
        const int c0 = ct * 64;
        if (ct > 0) __syncthreads();
#pragma unroll
        for (int k = 0; k < 16; ++k) {
            int idx = k * 256 + t;
            int r = idx >> 6, cc = idx & 63;
            tile[r][cc] = Fn[(size_t)(p0 + r) * 256 + c0 + cc];
        }
        __syncthreads();
#pragma unroll
        for (int k = 0; k < 2; ++k) {
            int u = k * 256 + t;
            int cc = u & 63, S = u >> 6;          // S in [0,8)
            int G = S ^ (cc & 7);
            uint4 pk;
            pk.x = pkbf2(tile[G * 8 + 0][cc], tile[G * 8 + 1][cc]);
            pk.y = pkbf2(tile[G * 8 + 2][cc], tile[G * 8 + 3][cc]);
            pk.z = pkbf2(tile[G * 8 + 4][cc], tile[G * 8 + 5][cc]);
            pk.w = pkbf2(tile[G * 8 + 6][cc], tile[G * 8 + 7][cc]);
            *(uint4*)&Gn[(c0 + cc) * 64 + S * 8] = pk;
        }
    }
}

// ---------- K4: out tile 128q x 256ch, p-step 64, DMA staging ----------
// v7: v6 structure at DOUBLE q-tile (128q per block, 256 blocks, 1/CU).
// Halves per-XCD L2 read amplification: 32 blocks/batch (not 64) each read
// the shared 32KB Gt + 8KB Q step-slices -> 1.28 MB/XCD/step (was 2.56).
// Wave split: S-phase (ps = w&3 p-strip) x (qh = w>>2 q-half of 64 rows,
// qt x4); PV wave owns 32-ch slice with 8 m-tiles (acc[8][2]).
__global__ __launch_bounds__(512, 2) void k4_attn(
    const u16* __restrict__ Q, const u16* __restrict__ Gt,
    const float* __restrict__ lgl, const float* __restrict__ mask,
    const float* __restrict__ ref, float* __restrict__ out) {
    const int t = threadIdx.x;
    const int w = t >> 6, L = t & 63, lane16 = L & 15, quad = L >> 4, l7 = lane16 & 7;
    const int bx = blockIdx.x;
    const int n = bx & 7, qb = bx >> 3;   // batch-per-XCD swizzle, qb in [0,32)
    const int q0 = qb << 7;               // 128 q rows per block
    const int ps = w & 3;                 // S-phase p-strip
    const int qh = w >> 2;                // S-phase q-half (64 rows)

    __shared__ u16 sGt[16384];   // 32 KB: step's 256ch x 64p (swizzled)
    __shared__ u16 sQp[4096];    // 8 KB: step's 64 p-rows of Q (swizzled)
    __shared__ u16 sP[8192];     // 16 KB: P' 128q x 64p (swizzled)

    const u16* Qn = Q + (size_t)n * 4096 * 64;
    const u16* Gtn = Gt + (size_t)n * 64 * 16384;
    const float* iln = lgl + n * 4096;

    // invariant B-frags: this wave's 64 q-rows of Q (its q-half)
    f16x8 bq[4][2];
#pragma unroll
    for (int qt = 0; qt < 4; ++qt) {
        const int row = q0 + qh * 64 + qt * 16 + lane16;
        bq[qt][0] = ldg8h(Qn + row * 64 + ((quad * 8) ^ (l7 * 8)));
        bq[qt][1] = ldg8h(Qn + row * 64 + ((32 + quad * 8) ^ (l7 * 8)));
    }

    // loop-invariant LDS addresses
    const int pl = ps * 16 + lane16;                      // S-phase A rows
    const int sA0 = pl * 64 + ((quad * 8) ^ (l7 * 8));
    const int sA1 = pl * 64 + ((32 + quad * 8) ^ (l7 * 8));
    int wrP[4];
#pragma unroll
    for (int qt = 0; qt < 4; ++qt)
        wrP[qt] = (qh * 64 + qt * 16 + lane16) * 64 +
                  ((ps * 16 + 8 * (quad >> 1)) ^ (l7 * 8)) + 4 * (quad & 1);
    const int dl = L * 8;                                  // DMA lane offset (elems)

    const f32x4 z4 = {0.f, 0.f, 0.f, 0.f};
    f32x4 acc[8][2];
#pragma unroll
    for (int a = 0; a < 8; ++a)
#pragma unroll
        for (int b = 0; b < 2; ++b) acc[a][b] = z4;

    // prologue: DMA sQp for step 0 (one 16B chunk per wave)
    gld16(Qn + w * 512 + dl, &sQp[w * 512]);
    __syncthreads();

#pragma unroll 1
    for (int i = 0; i < 64; ++i) {
        // DMA sGt for step i (PV(i-1) reads done before last barrier)
#pragma unroll
        for (int j = 0; j < 4; ++j) {
            const int c = w * 4 + j;
            gld16(Gtn + (size_t)i * 16384 + c * 512 + dl, &sGt[c * 512]);
        }
        // ---- S phase: wave (ps,qh) computes P' p-strip ps, q-half qh ----
        {
            f16x8 a0 = ldg8h(&sQp[sA0]);
            f16x8 a1 = ldg8h(&sQp[sA1]);
            float4 il4 = *(const float4*)(iln + i * 64 + ps * 16 + quad * 4);
            float lg0 = il4.x, lg1 = il4.y, lg2 = il4.z, lg3 = il4.w;
#pragma unroll
            for (int qt = 0; qt < 4; ++qt) {
                f32x4 z = z4;
                z = mfma_h(a0, bq[qt][0], z);
                z = mfma_h(a1, bq[qt][1], z);
                uint2 pk;
                pk.x = pkbf2(__builtin_exp2f(__builtin_fmaf(z[0], LOG2E, lg0)),
                             __builtin_exp2f(__builtin_fmaf(z[1], LOG2E, lg1)));
                pk.y = pkbf2(__builtin_exp2f(__builtin_fmaf(z[2], LOG2E, lg2)),
                             __builtin_exp2f(__builtin_fmaf(z[3], LOG2E, lg3)));
                *(uint2*)&sP[wrP[qt]] = pk;
            }
        }
        __syncthreads();   // drains sGt DMA; sP visible
        // DMA sQp for step i+1 (S(i) reads done)
        if (i + 1 < 64) {
            gld16(Qn + (size_t)(i + 1) * 4096 + w * 512 + dl, &sQp[w * 512]);
        }
        // ---- PV phase: wave owns ch slice [w*32, w*32+32) ----
#pragma unroll
        for (int h = 0; h < 2; ++h) {
            bf16x8 af[8], bb[2];
#pragma unroll
            for (int m = 0; m < 8; ++m)
                af[m] = ldg8b(&sP[(m * 16 + lane16) * 64 + ((h * 32 + quad * 8) ^ (l7 * 8))]);
#pragma unroll
            for (int nt = 0; nt < 2; ++nt)
                bb[nt] = ldg8b(&sGt[(w * 32 + nt * 16 + lane16) * 64 +
                                    ((h * 32 + quad * 8) ^ (l7 * 8))]);
#pragma unroll
            for (int nt = 0; nt < 2; ++nt)
#pragma unroll
                for (int m = 0; m < 8; ++m)
                    acc[m][nt] = mfma_bf(af[m], bb[nt], acc[m][nt]);
        }
        __syncthreads();   // drains sQp DMA; protects sP/sGt rewrite
    }

    // ---- epilogue: replicate the reference's reshape scramble ----
    // flat = ch*4096 + qb*128 + ql -> pixel = ch*16 + (qb>>1),
    // out channel = (qb&1)*128 + ql
    const int tb = qb >> 1;
    const int cb = (qb & 1) << 7;
    const float* maskn = mask + n * 4096;
    const float* refn = ref + (size_t)n * 4096 * 256;
    float* outn = out + (size_t)n * 4096 * 512;
#pragma unroll
    for (int nt = 0; nt < 2; ++nt) {
        const int ch = w * 32 + nt * 16 + lane16;
        const int pixel = ch * 16 + tb;
        const float m = maskn[pixel];
#pragma unroll
        for (int mt = 0; mt < 8; ++mt) {
            const int c4 = cb + mt * 16 + quad * 4;
            float4 r4 = *(const float4*)(refn + (size_t)pixel * 256 + c4);
            float a0 = acc[mt][nt][0], a1 = acc[mt][nt][1];
            float a2 = acc[mt][nt][2], a3 = acc[mt][nt][3];
            float4 a4 = {a0, a1, a2, a3};
            float4 bl4 = {m * a0 + (1.f - m) * r4.x,
                          m * a1 + (1.f - m) * r4.y,
                          m * a2 + (1.f - m) * r4.z,
                          m * a3 + (1.f - m) * r4.w};
            *(float4*)(outn + (size_t)pixel * 512 + 256 + c4) = a4;   // src_att
            *(float4*)(outn + (size_t)pixel * 512 + c4) = bl4;        // ex_guide_flow
        }
    }
}

extern "C" void kernel_launch(void* const* d_in, const int* in_sizes, int n_in,
                              void* d_out, int out_size, void* d_ws, size_t ws_size,
                              hipStream_t stream) {
    const float* mask = (const float*)d_in[0];   // (8,64,64) f32
    const float* F    = (const float*)d_in[1];   // (8,64,64,256) f32
    const float* ref  = (const float*)d_in[2];   // (8,64,64,256) f32
    const float* Wq   = (const float*)d_in[3];   // (256,64) f32
    float* out = (float*)d_out;                  // (8,64,64,512) f32
    char* ws = (char*)d_ws;

    u16*   Wthi = (u16*)ws;                                     // 32 KB
    u16*   Wtlo = (u16*)(ws + 32768);                           // 32 KB
    u16*   Qh   = (u16*)(ws + 65536);                           // 4 MB (fp16, swizzled)
    float* lgl  = (float*)(ws + 65536 + 4194304);               // 128 KB (-log2 of denom)
    u16*   Gt   = (u16*)(ws + 65536 + 4194304 + 131072);        // 16 MB (bf16, swizzled)

    k0_wt    <<<64,   256, 0, stream>>>(Wq, Wthi, Wtlo);
    k1_query <<<512,  256, 0, stream>>>(F, Wthi, Wtlo, Qh);
    k2_suminv<<<512,  512, 0, stream>>>(Qh, lgl);
    k3_gt    <<<512,  256, 0, stream>>>(F, Gt);
    k4_attn  <<<256,  512, 0, stream>>>(Qh, Gt, lgl, mask, ref, out);
}

// Round 8
// 268.128 us; speedup vs baseline: 1.1261x; 1.1261x over previous
//
#include <hip/hip_runtime.h>

typedef unsigned short u16;
typedef unsigned int u32;
typedef __attribute__((ext_vector_type(8))) __bf16 bf16x8;
typedef __attribute__((ext_vector_type(8))) _Float16 f16x8;
typedef __attribute__((ext_vector_type(4))) float f32x4;

// ---------- helpers ----------
__device__ __forceinline__ float b2f(u16 b) {
    union { u32 u; float f; } v; v.u = ((u32)b) << 16; return v.f;
}
__device__ __forceinline__ u16 f2bf(float f) {
    union { float f; u32 u; } v; v.f = f;
    u32 u = v.u;
    return (u16)((u + 0x7fffu + ((u >> 16) & 1u)) >> 16);  // RNE
}
__device__ __forceinline__ u16 f2h(float f) {
    _Float16 h = (_Float16)f;
    return __builtin_bit_cast(u16, h);
}
// packed pair -> u32 (compiler emits v_cvt_pk_bf16_f32)
__device__ __forceinline__ u32 pkbf2(float a, float b) {
    u16 x = __builtin_bit_cast(u16, (__bf16)a);
    u16 y = __builtin_bit_cast(u16, (__bf16)b);
    return (u32)x | ((u32)y << 16);
}
__device__ __forceinline__ bf16x8 ldg8b(const u16* p) {
    uint4 v = *(const uint4*)p;
    return __builtin_bit_cast(bf16x8, v);
}
__device__ __forceinline__ f16x8 ldg8h(const u16* p) {
    uint4 v = *(const uint4*)p;
    return __builtin_bit_cast(f16x8, v);
}
__device__ __forceinline__ f32x4 mfma_bf(bf16x8 a, bf16x8 b, f32x4 c) {
    return __builtin_amdgcn_mfma_f32_16x16x32_bf16(a, b, c, 0, 0, 0);
}
__device__ __forceinline__ f32x4 mfma_h(f16x8 a, f16x8 b, f32x4 c) {
    return __builtin_amdgcn_mfma_f32_16x16x32_f16(a, b, c, 0, 0, 0);
}
// async global->LDS: lds dest = wave-uniform base + lane*16
__device__ __forceinline__ void gld16(const u16* g, u16* l) {
    __builtin_amdgcn_global_load_lds(
        (const __attribute__((address_space(1))) u32*)g,
        (__attribute__((address_space(3))) u32*)l, 16, 0, 0);
}

// Q global layout: per batch, row p (4096): 64 fp16, elem slot = d ^ ((p&7)*8)
// Gt global layout: per (n, step s of 64 p): 16384 elems: ch*64 + ((pp&~7)^((ch&7)*8)) + (pp&7)

// ---------- K0: hi/lo bf16 split of W, transposed: Wt[d][c] ----------
__global__ void k0_wt(const float* __restrict__ Wq,
                      u16* __restrict__ Wthi, u16* __restrict__ Wtlo) {
    int idx = blockIdx.x * 256 + threadIdx.x;   // 64 blocks -> 16384
    int c = idx >> 6, d = idx & 63;
    float w = Wq[idx];
    u16 hi = f2bf(w);
    float rem = w - b2f(hi);
    Wthi[d * 256 + c] = hi;
    Wtlo[d * 256 + c] = f2bf(rem);
}

// ---------- K13: fused k1 (Q = F*W) + k3 (Gt transpose) ----------
// k1 and k3 blocks partition F identically (64 rows x 256 ch per block).
// Stage each 64-row x 64-ch F chunk to LDS ONCE; k1's A-fragments read from
// LDS (was: second global F sweep) and k3's transpose-write reads the same
// tile. Saves one full 32MB F read + one launch; overlaps transpose memory
// work under the MFMA/VALU of the query GEMM.
__global__ __launch_bounds__(256) void k13_query_gt(
    const float* __restrict__ F, const u16* __restrict__ Wthi,
    const u16* __restrict__ Wtlo, u16* __restrict__ Qh,
    u16* __restrict__ Gt) {
    const int t = threadIdx.x;
    const int w = t >> 6, L = t & 63, lane16 = L & 15, quad = L >> 4;
    const int bx = blockIdx.x;                 // 512 = 8 n * 64 s
    const int R0 = bx * 64;                    // global F row (n*4096 + s*64)
    const int n = bx >> 6, s = bx & 63;

    __shared__ float tile[64][68];             // 17 KB, stride 68 keeps 16B align
    const float* Fn = F + (size_t)R0 * 256;
    u16* Gn = Gt + (size_t)(n * 64 + s) * 16384;

    const f32x4 z4 = {0.f, 0.f, 0.f, 0.f};
    f32x4 acc[4] = {z4, z4, z4, z4};
    union U8 { bf16x8 v; u16 s[8]; };

#pragma unroll 1
    for (int ct = 0; ct < 4; ++ct) {
        const int c0 = ct * 64;
        if (ct > 0) __syncthreads();           // prev chunk's readers done
        // ---- stage F chunk: 64 rows x 64 ch ----
#pragma unroll
        for (int k = 0; k < 16; ++k) {
            int idx = k * 256 + t;
            int r = idx >> 6, cc = idx & 63;
            tile[r][cc] = Fn[(size_t)r * 256 + c0 + cc];
        }
        __syncthreads();
        // ---- k3 part: swizzled bf16 transpose-write of this chunk ----
#pragma unroll
        for (int k = 0; k < 2; ++k) {
            int u = k * 256 + t;
            int cc = u & 63, S = u >> 6;       // S in [0,8)
            int G = S ^ (cc & 7);
            uint4 pk;
            pk.x = pkbf2(tile[G * 8 + 0][cc], tile[G * 8 + 1][cc]);
            pk.y = pkbf2(tile[G * 8 + 2][cc], tile[G * 8 + 3][cc]);
            pk.z = pkbf2(tile[G * 8 + 4][cc], tile[G * 8 + 5][cc]);
            pk.w = pkbf2(tile[G * 8 + 6][cc], tile[G * 8 + 7][cc]);
            *(uint4*)&Gn[(c0 + cc) * 64 + S * 8] = pk;
        }
        // ---- k1 part: 2 ks-chunks of the K=256 contraction, A from LDS ----
#pragma unroll
        for (int kk = 0; kk < 2; ++kk) {
            const int ks = ct * 2 + kk;
            const float* tp = &tile[w * 16 + lane16][kk * 32 + quad * 8];
            float4 x0 = *(const float4*)tp;
            float4 x1 = *(const float4*)(tp + 4);
            float xs[8] = {x0.x, x0.y, x0.z, x0.w, x1.x, x1.y, x1.z, x1.w};
            U8 ahi, alo;
#pragma unroll
            for (int j = 0; j < 8; ++j) {
                u16 h = f2bf(xs[j]);
                ahi.s[j] = h;
                alo.s[j] = f2bf(xs[j] - b2f(h));
            }
#pragma unroll
            for (int nt = 0; nt < 4; ++nt) {
                const int off = (nt * 16 + lane16) * 256 + ks * 32 + quad * 8;
                bf16x8 bh = ldg8b(Wthi + off);
                bf16x8 bl = ldg8b(Wtlo + off);
                acc[nt] = mfma_bf(ahi.v, bh, acc[nt]);
                acc[nt] = mfma_bf(alo.v, bh, acc[nt]);
                acc[nt] = mfma_bf(ahi.v, bl, acc[nt]);
            }
        }
    }
    // ---- Qh epilogue (identical to k1) ----
    const int orow = R0 + w * 16 + quad * 4;
#pragma unroll
    for (int nt = 0; nt < 4; ++nt) {
        const int d = nt * 16 + lane16;
#pragma unroll
        for (int r = 0; r < 4; ++r) {
            const int p = orow + r;
            Qh[(size_t)p * 64 + (d ^ ((p & 7) << 3))] = f2h(acc[nt][r]);
        }
    }
}

// ---------- K2: inv_l[p] = 1 / sum_q exp(Q_p . Q_q), p-tile 32, grid 1024 ----------
__global__ __launch_bounds__(256) void k2_suminv(
    const u16* __restrict__ Q, float* __restrict__ inv_l) {
    const int t = threadIdx.x;
    const int w = t >> 6, L = t & 63, lane16 = L & 15, quad = L >> 4, l7 = lane16 & 7;
    const int bx = blockIdx.x;
    const int n = bx & 7, pb = bx >> 3;   // batch-per-XCD swizzle
    const int P0 = pb * 32;
    const u16* Qn = Q + (size_t)n * 4096 * 64;

    f16x8 ap[2][2];
#pragma unroll
    for (int st = 0; st < 2; ++st) {
        const int row = P0 + st * 16 + lane16;
        ap[st][0] = ldg8h(Qn + row * 64 + ((quad * 8) ^ (l7 * 8)));
        ap[st][1] = ldg8h(Qn + row * 64 + ((32 + quad * 8) ^ (l7 * 8)));
    }
    float sums[2][4];
#pragma unroll
    for (int st = 0; st < 2; ++st)
#pragma unroll
        for (int r = 0; r < 4; ++r) sums[st][r] = 0.f;

    const f32x4 z4 = {0.f, 0.f, 0.f, 0.f};
    for (int s = 0; s < 32; ++s) {
#pragma unroll
        for (int nt = 0; nt < 2; ++nt) {
            const int qr = w * 1024 + s * 32 + nt * 16 + lane16;
            f16x8 b0 = ldg8h(Qn + qr * 64 + ((quad * 8) ^ (l7 * 8)));
            f16x8 b1 = ldg8h(Qn + qr * 64 + ((32 + quad * 8) ^ (l7 * 8)));
#pragma unroll
            for (int st = 0; st < 2; ++st) {
                f32x4 z = z4;
                z = mfma_h(ap[st][0], b0, z);
                z = mfma_h(ap[st][1], b1, z);
                sums[st][0] += __expf(z[0]);
                sums[st][1] += __expf(z[1]);
                sums[st][2] += __expf(z[2]);
                sums[st][3] += __expf(z[3]);
            }
        }
    }
    __shared__ float red[4][32];
#pragma unroll
    for (int st = 0; st < 2; ++st)
#pragma unroll
        for (int r = 0; r < 4; ++r) {
            float v = sums[st][r];
            v += __shfl_xor(v, 1);
            v += __shfl_xor(v, 2);
            v += __shfl_xor(v, 4);
            v += __shfl_xor(v, 8);
            if (lane16 == 0) red[w][st * 16 + quad * 4 + r] = v;
        }
    __syncthreads();
    if (t < 32) {
        float tot = red[0][t] + red[1][t] + red[2][t] + red[3][t];
        inv_l[n * 4096 + P0 + t] = 1.0f / tot;
    }
}

// ---------- K4: out tile 64q x 256ch, p-step 64, DMA staging, swapped-S ----------
// (round-0 verbatim: the proven 128us structure)
__global__ __launch_bounds__(256, 2) void k4_attn(
    const u16* __restrict__ Q, const u16* __restrict__ Gt,
    const float* __restrict__ invl, const float* __restrict__ mask,
    const float* __restrict__ ref, float* __restrict__ out) {
    const int t = threadIdx.x;
    const int w = t >> 6, L = t & 63, lane16 = L & 15, quad = L >> 4, l7 = lane16 & 7;
    const int bx = blockIdx.x;
    const int n = bx & 7, qb = bx >> 3;   // batch-per-XCD swizzle
    const int q0 = qb << 6;

    __shared__ u16 sGt[16384];   // 32 KB: step's 256ch x 64p (swizzled)
    __shared__ u16 sQp[4096];    // 8 KB: step's 64 p-rows of Q (swizzled)
    __shared__ u16 sP[4096];     // 8 KB: P' 64q x 64p (swizzled)

    const u16* Qn = Q + (size_t)n * 4096 * 64;
    const u16* Gtn = Gt + (size_t)n * 64 * 16384;
    const float* iln = invl + n * 4096;

    // invariant B-frags: this block's 64 q-rows of Q
    f16x8 bq[4][2];
#pragma unroll
    for (int qt = 0; qt < 4; ++qt) {
        const int row = q0 + qt * 16 + lane16;
        bq[qt][0] = ldg8h(Qn + row * 64 + ((quad * 8) ^ (l7 * 8)));
        bq[qt][1] = ldg8h(Qn + row * 64 + ((32 + quad * 8) ^ (l7 * 8)));
    }

    // loop-invariant LDS addresses
    const int pl = w * 16 + lane16;                       // S-phase A rows (p-strip w)
    const int sA0 = pl * 64 + ((quad * 8) ^ (l7 * 8));
    const int sA1 = pl * 64 + ((32 + quad * 8) ^ (l7 * 8));
    int wrP[4];
#pragma unroll
    for (int qt = 0; qt < 4; ++qt)
        wrP[qt] = (qt * 16 + lane16) * 64 +
                  ((w * 16 + 8 * (quad >> 1)) ^ (l7 * 8)) + 4 * (quad & 1);
    const int dl = L * 8;                                  // DMA lane offset (elems)

    const f32x4 z4 = {0.f, 0.f, 0.f, 0.f};
    f32x4 acc[4][4];
#pragma unroll
    for (int a = 0; a < 4; ++a)
#pragma unroll
        for (int b = 0; b < 4; ++b) acc[a][b] = z4;

    // prologue: DMA sQp for step 0
#pragma unroll
    for (int j = 0; j < 2; ++j) {
        const int c = w * 2 + j;
        gld16(Qn + c * 512 + dl, &sQp[c * 512]);
    }
    __syncthreads();

#pragma unroll 1
    for (int i = 0; i < 64; ++i) {
        // DMA sGt for step i (PV(i-1) reads done before last barrier)
#pragma unroll
        for (int j = 0; j < 8; ++j) {
            const int c = w * 8 + j;
            gld16(Gtn + (size_t)i * 16384 + c * 512 + dl, &sGt[c * 512]);
        }
        // ---- S phase: wave w computes P' rows p-strip w, all 64 q ----
        {
            f16x8 a0 = ldg8h(&sQp[sA0]);
            f16x8 a1 = ldg8h(&sQp[sA1]);
            float4 il4 = *(const float4*)(iln + i * 64 + w * 16 + quad * 4);
#pragma unroll
            for (int qt = 0; qt < 4; ++qt) {
                f32x4 z = z4;
                z = mfma_h(a0, bq[qt][0], z);
                z = mfma_h(a1, bq[qt][1], z);
                ushort4 pk;
                pk.x = f2bf(__expf(z[0]) * il4.x);
                pk.y = f2bf(__expf(z[1]) * il4.y);
                pk.z = f2bf(__expf(z[2]) * il4.z);
                pk.w = f2bf(__expf(z[3]) * il4.w);
                *(ushort4*)&sP[wrP[qt]] = pk;
            }
        }
        __syncthreads();   // drains sGt DMA; sP visible
        // DMA sQp for step i+1 (S(i) reads done)
        if (i + 1 < 64) {
#pragma unroll
            for (int j = 0; j < 2; ++j) {
                const int c = w * 2 + j;
                gld16(Qn + (size_t)(i + 1) * 4096 + c * 512 + dl, &sQp[c * 512]);
            }
        }
        // ---- PV phase: wave owns ch slice [w*64, w*64+64) ----
#pragma unroll
        for (int h = 0; h < 2; ++h) {
            bf16x8 af[4], bb[4];
#pragma unroll
            for (int m = 0; m < 4; ++m)
                af[m] = ldg8b(&sP[(m * 16 + lane16) * 64 + ((h * 32 + quad * 8) ^ (l7 * 8))]);
#pragma unroll
            for (int nt = 0; nt < 4; ++nt)
                bb[nt] = ldg8b(&sGt[(w * 64 + nt * 16 + lane16) * 64 +
                                    ((h * 32 + quad * 8) ^ (l7 * 8))]);
#pragma unroll
            for (int nt = 0; nt < 4; ++nt)
#pragma unroll
                for (int m = 0; m < 4; ++m)
                    acc[m][nt] = mfma_bf(af[m], bb[nt], acc[m][nt]);
        }
        __syncthreads();   // drains sQp DMA; protects sP/sGt rewrite
    }

    // ---- epilogue: replicate the reference's reshape scramble ----
    // out pixel = ch*16 + (qb>>2), out channel = (qb&3)*64 + q_local
    const int tb = qb >> 2;
    const int cb = (qb & 3) * 64;
    const float* maskn = mask + n * 4096;
    const float* refn = ref + (size_t)n * 4096 * 256;
    float* outn = out + (size_t)n * 4096 * 512;
#pragma unroll
    for (int nt = 0; nt < 4; ++nt) {
        const int ch = w * 64 + nt * 16 + lane16;
        const int pixel = ch * 16 + tb;
        const float m = maskn[pixel];
#pragma unroll
        for (int mt = 0; mt < 4; ++mt) {
            const int c4 = cb + mt * 16 + quad * 4;
            float4 r4 = *(const float4*)(refn + (size_t)pixel * 256 + c4);
            float a0 = acc[mt][nt][0], a1 = acc[mt][nt][1];
            float a2 = acc[mt][nt][2], a3 = acc[mt][nt][3];
            float4 a4 = {a0, a1, a2, a3};
            float4 bl4 = {m * a0 + (1.f - m) * r4.x,
                          m * a1 + (1.f - m) * r4.y,
                          m * a2 + (1.f - m) * r4.z,
                          m * a3 + (1.f - m) * r4.w};
            *(float4*)(outn + (size_t)pixel * 512 + 256 + c4) = a4;   // src_att
            *(float4*)(outn + (size_t)pixel * 512 + c4) = bl4;        // ex_guide_flow
        }
    }
}

extern "C" void kernel_launch(void* const* d_in, const int* in_sizes, int n_in,
                              void* d_out, int out_size, void* d_ws, size_t ws_size,
                              hipStream_t stream) {
    const float* mask = (const float*)d_in[0];   // (8,64,64) f32
    const float* F    = (const float*)d_in[1];   // (8,64,64,256) f32
    const float* ref  = (const float*)d_in[2];   // (8,64,64,256) f32
    const float* Wq   = (const float*)d_in[3];   // (256,64) f32
    float* out = (float*)d_out;                  // (8,64,64,512) f32
    char* ws = (char*)d_ws;

    u16*   Wthi = (u16*)ws;                                     // 32 KB
    u16*   Wtlo = (u16*)(ws + 32768);                           // 32 KB
    u16*   Qh   = (u16*)(ws + 65536);                           // 4 MB (fp16, swizzled)
    float* invl = (float*)(ws + 65536 + 4194304);               // 128 KB
    u16*   Gt   = (u16*)(ws + 65536 + 4194304 + 131072);        // 16 MB (bf16, swizzled)

    k0_wt        <<<64,   256, 0, stream>>>(Wq, Wthi, Wtlo);
    k13_query_gt <<<512,  256, 0, stream>>>(F, Wthi, Wtlo, Qh, Gt);
    k2_suminv    <<<1024, 256, 0, stream>>>(Qh, invl);
    k4_attn      <<<512,  256, 0, stream>>>(Qh, Gt, invl, mask, ref, out);
}

// Round 9
// 267.462 us; speedup vs baseline: 1.1289x; 1.0025x over previous
//
#include <hip/hip_runtime.h>

typedef unsigned short u16;
typedef unsigned int u32;
typedef __attribute__((ext_vector_type(8))) __bf16 bf16x8;
typedef __attribute__((ext_vector_type(8))) _Float16 f16x8;
typedef __attribute__((ext_vector_type(4))) float f32x4;

// ---------- helpers ----------
__device__ __forceinline__ float b2f(u16 b) {
    union { u32 u; float f; } v; v.u = ((u32)b) << 16; return v.f;
}
__device__ __forceinline__ u16 f2bf(float f) {
    union { float f; u32 u; } v; v.f = f;
    u32 u = v.u;
    return (u16)((u + 0x7fffu + ((u >> 16) & 1u)) >> 16);  // RNE
}
__device__ __forceinline__ u16 f2h(float f) {
    _Float16 h = (_Float16)f;
    return __builtin_bit_cast(u16, h);
}
// packed pair -> u32 (compiler emits v_cvt_pk_bf16_f32)
__device__ __forceinline__ u32 pkbf2(float a, float b) {
    u16 x = __builtin_bit_cast(u16, (__bf16)a);
    u16 y = __builtin_bit_cast(u16, (__bf16)b);
    return (u32)x | ((u32)y << 16);
}
__device__ __forceinline__ bf16x8 ldg8b(const u16* p) {
    uint4 v = *(const uint4*)p;
    return __builtin_bit_cast(bf16x8, v);
}
__device__ __forceinline__ f16x8 ldg8h(const u16* p) {
    uint4 v = *(const uint4*)p;
    return __builtin_bit_cast(f16x8, v);
}
__device__ __forceinline__ f32x4 mfma_bf(bf16x8 a, bf16x8 b, f32x4 c) {
    return __builtin_amdgcn_mfma_f32_16x16x32_bf16(a, b, c, 0, 0, 0);
}
__device__ __forceinline__ f32x4 mfma_h(f16x8 a, f16x8 b, f32x4 c) {
    return __builtin_amdgcn_mfma_f32_16x16x32_f16(a, b, c, 0, 0, 0);
}
// async global->LDS: lds dest = wave-uniform base + lane*16
__device__ __forceinline__ void gld16(const u16* g, u16* l) {
    __builtin_amdgcn_global_load_lds(
        (const __attribute__((address_space(1))) u32*)g,
        (__attribute__((address_space(3))) u32*)l, 16, 0, 0);
}

// Q global layout: per batch, row p (4096): 64 fp16, elem slot = d ^ ((p&7)*8)
// Gt global layout: per (n, step s of 64 p): 16384 elems: ch*64 + ((pp&~7)^((ch&7)*8)) + (pp&7)

// ---------- K0: hi/lo bf16 split of W, transposed: Wt[d][c] ----------
__global__ void k0_wt(const float* __restrict__ Wq,
                      u16* __restrict__ Wthi, u16* __restrict__ Wtlo) {
    int idx = blockIdx.x * 256 + threadIdx.x;   // 64 blocks -> 16384
    int c = idx >> 6, d = idx & 63;
    float w = Wq[idx];
    u16 hi = f2bf(w);
    float rem = w - b2f(hi);
    Wthi[d * 256 + c] = hi;
    Wtlo[d * 256 + c] = f2bf(rem);
}

// ---------- K13: fused k1 (Q = F*W) + k3 (Gt transpose) ----------
// Stage each 64-row x 64-ch F chunk to LDS ONCE (float4-vectorized: this
// kernel is issue-bound, not BW-bound -- 4 dwordx4/thread instead of 16
// dword); k1's A-fragments read from LDS and k3's transpose-write reads the
// same tile.
__global__ __launch_bounds__(256) void k13_query_gt(
    const float* __restrict__ F, const u16* __restrict__ Wthi,
    const u16* __restrict__ Wtlo, u16* __restrict__ Qh,
    u16* __restrict__ Gt) {
    const int t = threadIdx.x;
    const int w = t >> 6, L = t & 63, lane16 = L & 15, quad = L >> 4;
    const int bx = blockIdx.x;                 // 512 = 8 n * 64 s
    const int R0 = bx * 64;                    // global F row (n*4096 + s*64)
    const int n = bx >> 6, s = bx & 63;

    __shared__ float tile[64][68];             // 17 KB; 68*4B=272B row stride (16B-mult)
    const float* Fn = F + (size_t)R0 * 256;
    u16* Gn = Gt + (size_t)(n * 64 + s) * 16384;

    const f32x4 z4 = {0.f, 0.f, 0.f, 0.f};
    f32x4 acc[4] = {z4, z4, z4, z4};
    union U8 { bf16x8 v; u16 s[8]; };

#pragma unroll 1
    for (int ct = 0; ct < 4; ++ct) {
        const int c0 = ct * 64;
        if (ct > 0) __syncthreads();           // prev chunk's readers done
        // ---- stage F chunk: 64 rows x 64 ch, float4 ----
#pragma unroll
        for (int k = 0; k < 4; ++k) {
            int idx = k * 256 + t;             // [0,1024)
            int r = idx >> 4, c4 = (idx & 15) << 2;
            *(float4*)&tile[r][c4] =
                *(const float4*)&Fn[(size_t)r * 256 + c0 + c4];
        }
        __syncthreads();
        // ---- k3 part: swizzled bf16 transpose-write of this chunk ----
#pragma unroll
        for (int k = 0; k < 2; ++k) {
            int u = k * 256 + t;
            int cc = u & 63, S = u >> 6;       // S in [0,8)
            int G = S ^ (cc & 7);
            uint4 pk;
            pk.x = pkbf2(tile[G * 8 + 0][cc], tile[G * 8 + 1][cc]);
            pk.y = pkbf2(tile[G * 8 + 2][cc], tile[G * 8 + 3][cc]);
            pk.z = pkbf2(tile[G * 8 + 4][cc], tile[G * 8 + 5][cc]);
            pk.w = pkbf2(tile[G * 8 + 6][cc], tile[G * 8 + 7][cc]);
            *(uint4*)&Gn[(c0 + cc) * 64 + S * 8] = pk;
        }
        // ---- k1 part: 2 ks-chunks of the K=256 contraction, A from LDS ----
#pragma unroll
        for (int kk = 0; kk < 2; ++kk) {
            const int ks = ct * 2 + kk;
            const float* tp = &tile[w * 16 + lane16][kk * 32 + quad * 8];
            float4 x0 = *(const float4*)tp;
            float4 x1 = *(const float4*)(tp + 4);
            float xs[8] = {x0.x, x0.y, x0.z, x0.w, x1.x, x1.y, x1.z, x1.w};
            U8 ahi, alo;
#pragma unroll
            for (int j = 0; j < 8; ++j) {
                u16 h = f2bf(xs[j]);
                ahi.s[j] = h;
                alo.s[j] = f2bf(xs[j] - b2f(h));
            }
#pragma unroll
            for (int nt = 0; nt < 4; ++nt) {
                const int off = (nt * 16 + lane16) * 256 + ks * 32 + quad * 8;
                bf16x8 bh = ldg8b(Wthi + off);
                bf16x8 bl = ldg8b(Wtlo + off);
                acc[nt] = mfma_bf(ahi.v, bh, acc[nt]);
                acc[nt] = mfma_bf(alo.v, bh, acc[nt]);
                acc[nt] = mfma_bf(ahi.v, bl, acc[nt]);
            }
        }
    }
    // ---- Qh epilogue (identical to k1) ----
    const int orow = R0 + w * 16 + quad * 4;
#pragma unroll
    for (int nt = 0; nt < 4; ++nt) {
        const int d = nt * 16 + lane16;
#pragma unroll
        for (int r = 0; r < 4; ++r) {
            const int p = orow + r;
            Qh[(size_t)p * 64 + (d ^ ((p & 7) << 3))] = f2h(acc[nt][r]);
        }
    }
}

// ---------- K2: inv_l[p] = 1 / sum_q exp(Q_p . Q_q) ----------
// v9: p-tile 64 (was 32), grid 512 (was 1024). Same per-thread exp/MFMA
// work per q, but HALF the blocks -> half the total wave-work and half the
// redundant all-Q L2 sweeps (512 -> 256 MB). Wave w sweeps q in
// [w*1024,(w+1)*1024); 4 p-subtiles of 16 in registers.
__global__ __launch_bounds__(256) void k2_suminv(
    const u16* __restrict__ Q, float* __restrict__ inv_l) {
    const int t = threadIdx.x;
    const int w = t >> 6, L = t & 63, lane16 = L & 15, quad = L >> 4, l7 = lane16 & 7;
    const int bx = blockIdx.x;            // 512 = 8 n * 64 pb
    const int n = bx & 7, pb = bx >> 3;   // batch-per-XCD swizzle
    const int P0 = pb * 64;
    const u16* Qn = Q + (size_t)n * 4096 * 64;

    f16x8 ap[4][2];
#pragma unroll
    for (int st = 0; st < 4; ++st) {
        const int row = P0 + st * 16 + lane16;
        ap[st][0] = ldg8h(Qn + row * 64 + ((quad * 8) ^ (l7 * 8)));
        ap[st][1] = ldg8h(Qn + row * 64 + ((32 + quad * 8) ^ (l7 * 8)));
    }
    float sums[4][4];
#pragma unroll
    for (int st = 0; st < 4; ++st)
#pragma unroll
        for (int r = 0; r < 4; ++r) sums[st][r] = 0.f;

    const f32x4 z4 = {0.f, 0.f, 0.f, 0.f};
    for (int s = 0; s < 16; ++s) {
#pragma unroll
        for (int nt = 0; nt < 4; ++nt) {
            const int qr = w * 1024 + s * 64 + nt * 16 + lane16;
            f16x8 b0 = ldg8h(Qn + qr * 64 + ((quad * 8) ^ (l7 * 8)));
            f16x8 b1 = ldg8h(Qn + qr * 64 + ((32 + quad * 8) ^ (l7 * 8)));
#pragma unroll
            for (int st = 0; st < 4; ++st) {
                f32x4 z = z4;
                z = mfma_h(ap[st][0], b0, z);
                z = mfma_h(ap[st][1], b1, z);
                sums[st][0] += __expf(z[0]);
                sums[st][1] += __expf(z[1]);
                sums[st][2] += __expf(z[2]);
                sums[st][3] += __expf(z[3]);
            }
        }
    }
    __shared__ float red[4][64];
#pragma unroll
    for (int st = 0; st < 4; ++st)
#pragma unroll
        for (int r = 0; r < 4; ++r) {
            float v = sums[st][r];
            v += __shfl_xor(v, 1);
            v += __shfl_xor(v, 2);
            v += __shfl_xor(v, 4);
            v += __shfl_xor(v, 8);
            if (lane16 == 0) red[w][st * 16 + quad * 4 + r] = v;
        }
    __syncthreads();
    if (t < 64) {
        float tot = red[0][t] + red[1][t] + red[2][t] + red[3][t];
        inv_l[n * 4096 + P0 + t] = 1.0f / tot;
    }
}

// ---------- K4: out tile 64q x 256ch, p-step 64, DMA staging, swapped-S ----------
// (round-0 verbatim: the proven 128us structure -- FROZEN as control)
__global__ __launch_bounds__(256, 2) void k4_attn(
    const u16* __restrict__ Q, const u16* __restrict__ Gt,
    const float* __restrict__ invl, const float* __restrict__ mask,
    const float* __restrict__ ref, float* __restrict__ out) {
    const int t = threadIdx.x;
    const int w = t >> 6, L = t & 63, lane16 = L & 15, quad = L >> 4, l7 = lane16 & 7;
    const int bx = blockIdx.x;
    const int n = bx & 7, qb = bx >> 3;   // batch-per-XCD swizzle
    const int q0 = qb << 6;

    __shared__ u16 sGt[16384];   // 32 KB: step's 256ch x 64p (swizzled)
    __shared__ u16 sQp[4096];    // 8 KB: step's 64 p-rows of Q (swizzled)
    __shared__ u16 sP[4096];     // 8 KB: P' 64q x 64p (swizzled)

    const u16* Qn = Q + (size_t)n * 4096 * 64;
    const u16* Gtn = Gt + (size_t)n * 64 * 16384;
    const float* iln = invl + n * 4096;

    // invariant B-frags: this block's 64 q-rows of Q
    f16x8 bq[4][2];
#pragma unroll
    for (int qt = 0; qt < 4; ++qt) {
        const int row = q0 + qt * 16 + lane16;
        bq[qt][0] = ldg8h(Qn + row * 64 + ((quad * 8) ^ (l7 * 8)));
        bq[qt][1] = ldg8h(Qn + row * 64 + ((32 + quad * 8) ^ (l7 * 8)));
    }

    // loop-invariant LDS addresses
    const int pl = w * 16 + lane16;                       // S-phase A rows (p-strip w)
    const int sA0 = pl * 64 + ((quad * 8) ^ (l7 * 8));
    const int sA1 = pl * 64 + ((32 + quad * 8) ^ (l7 * 8));
    int wrP[4];
#pragma unroll
    for (int qt = 0; qt < 4; ++qt)
        wrP[qt] = (qt * 16 + lane16) * 64 +
                  ((w * 16 + 8 * (quad >> 1)) ^ (l7 * 8)) + 4 * (quad & 1);
    const int dl = L * 8;                                  // DMA lane offset (elems)

    const f32x4 z4 = {0.f, 0.f, 0.f, 0.f};
    f32x4 acc[4][4];
#pragma unroll
    for (int a = 0; a < 4; ++a)
#pragma unroll
        for (int b = 0; b < 4; ++b) acc[a][b] = z4;

    // prologue: DMA sQp for step 0
#pragma unroll
    for (int j = 0; j < 2; ++j) {
        const int c = w * 2 + j;
        gld16(Qn + c * 512 + dl, &sQp[c * 512]);
    }
    __syncthreads();

#pragma unroll 1
    for (int i = 0; i < 64; ++i) {
        // DMA sGt for step i (PV(i-1) reads done before last barrier)
#pragma unroll
        for (int j = 0; j < 8; ++j) {
            const int c = w * 8 + j;
            gld16(Gtn + (size_t)i * 16384 + c * 512 + dl, &sGt[c * 512]);
        }
        // ---- S phase: wave w computes P' rows p-strip w, all 64 q ----
        {
            f16x8 a0 = ldg8h(&sQp[sA0]);
            f16x8 a1 = ldg8h(&sQp[sA1]);
            float4 il4 = *(const float4*)(iln + i * 64 + w * 16 + quad * 4);
#pragma unroll
            for (int qt = 0; qt < 4; ++qt) {
                f32x4 z = z4;
                z = mfma_h(a0, bq[qt][0], z);
                z = mfma_h(a1, bq[qt][1], z);
                ushort4 pk;
                pk.x = f2bf(__expf(z[0]) * il4.x);
                pk.y = f2bf(__expf(z[1]) * il4.y);
                pk.z = f2bf(__expf(z[2]) * il4.z);
                pk.w = f2bf(__expf(z[3]) * il4.w);
                *(ushort4*)&sP[wrP[qt]] = pk;
            }
        }
        __syncthreads();   // drains sGt DMA; sP visible
        // DMA sQp for step i+1 (S(i) reads done)
        if (i + 1 < 64) {
#pragma unroll
            for (int j = 0; j < 2; ++j) {
                const int c = w * 2 + j;
                gld16(Qn + (size_t)(i + 1) * 4096 + c * 512 + dl, &sQp[c * 512]);
            }
        }
        // ---- PV phase: wave owns ch slice [w*64, w*64+64) ----
#pragma unroll
        for (int h = 0; h < 2; ++h) {
            bf16x8 af[4], bb[4];
#pragma unroll
            for (int m = 0; m < 4; ++m)
                af[m] = ldg8b(&sP[(m * 16 + lane16) * 64 + ((h * 32 + quad * 8) ^ (l7 * 8))]);
#pragma unroll
            for (int nt = 0; nt < 4; ++nt)
                bb[nt] = ldg8b(&sGt[(w * 64 + nt * 16 + lane16) * 64 +
                                    ((h * 32 + quad * 8) ^ (l7 * 8))]);
#pragma unroll
            for (int nt = 0; nt < 4; ++nt)
#pragma unroll
                for (int m = 0; m < 4; ++m)
                    acc[m][nt] = mfma_bf(af[m], bb[nt], acc[m][nt]);
        }
        __syncthreads();   // drains sQp DMA; protects sP/sGt rewrite
    }

    // ---- epilogue: replicate the reference's reshape scramble ----
    // out pixel = ch*16 + (qb>>2), out channel = (qb&3)*64 + q_local
    const int tb = qb >> 2;
    const int cb = (qb & 3) * 64;
    const float* maskn = mask + n * 4096;
    const float* refn = ref + (size_t)n * 4096 * 256;
    float* outn = out + (size_t)n * 4096 * 512;
#pragma unroll
    for (int nt = 0; nt < 4; ++nt) {
        const int ch = w * 64 + nt * 16 + lane16;
        const int pixel = ch * 16 + tb;
        const float m = maskn[pixel];
#pragma unroll
        for (int mt = 0; mt < 4; ++mt) {
            const int c4 = cb + mt * 16 + quad * 4;
            float4 r4 = *(const float4*)(refn + (size_t)pixel * 256 + c4);
            float a0 = acc[mt][nt][0], a1 = acc[mt][nt][1];
            float a2 = acc[mt][nt][2], a3 = acc[mt][nt][3];
            float4 a4 = {a0, a1, a2, a3};
            float4 bl4 = {m * a0 + (1.f - m) * r4.x,
                          m * a1 + (1.f - m) * r4.y,
                          m * a2 + (1.f - m) * r4.z,
                          m * a3 + (1.f - m) * r4.w};
            *(float4*)(outn + (size_t)pixel * 512 + 256 + c4) = a4;   // src_att
            *(float4*)(outn + (size_t)pixel * 512 + c4) = bl4;        // ex_guide_flow
        }
    }
}

extern "C" void kernel_launch(void* const* d_in, const int* in_sizes, int n_in,
                              void* d_out, int out_size, void* d_ws, size_t ws_size,
                              hipStream_t stream) {
    const float* mask = (const float*)d_in[0];   // (8,64,64) f32
    const float* F    = (const float*)d_in[1];   // (8,64,64,256) f32
    const float* ref  = (const float*)d_in[2];   // (8,64,64,256) f32
    const float* Wq   = (const float*)d_in[3];   // (256,64) f32
    float* out = (float*)d_out;                  // (8,64,64,512) f32
    char* ws = (char*)d_ws;

    u16*   Wthi = (u16*)ws;                                     // 32 KB
    u16*   Wtlo = (u16*)(ws + 32768);                           // 32 KB
    u16*   Qh   = (u16*)(ws + 65536);                           // 4 MB (fp16, swizzled)
    float* invl = (float*)(ws + 65536 + 4194304);               // 128 KB
    u16*   Gt   = (u16*)(ws + 65536 + 4194304 + 131072);        // 16 MB (bf16, swizzled)

    k0_wt        <<<64,  256, 0, stream>>>(Wq, Wthi, Wtlo);
    k13_query_gt <<<512, 256, 0, stream>>>(F, Wthi, Wtlo, Qh, Gt);
    k2_suminv    <<<512, 256, 0, stream>>>(Qh, invl);
    k4_attn      <<<512, 256, 0, stream>>>(Qh, Gt, invl, mask, ref, out);
}